// Round 1
// baseline (552.204 us; speedup 1.0000x reference)
//
#include <hip/hip_runtime.h>
#include <stdint.h>

#define DEV __device__ __forceinline__

using f32x4 = __attribute__((ext_vector_type(4))) float;
using s16x8 = __attribute__((ext_vector_type(8))) short;

DEV uint16_t f2bf(float f) {
  union { float f; uint32_t u; } v; v.f = f;
  uint32_t r = v.u + 0x7fffu + ((v.u >> 16) & 1u);  // round-to-nearest-even
  return (uint16_t)(r >> 16);
}
DEV float bf2f(uint16_t h) {
  union { uint32_t u; float f; } v; v.u = (uint32_t)h << 16;
  return v.f;
}
DEV uint32_t pack2(float a, float b) {
  return (uint32_t)f2bf(a) | ((uint32_t)f2bf(b) << 16);
}

// async global->LDS, 16B per lane; LDS dest = wave-uniform base + lane*16
DEV void gload_lds16(const void* g, void* l) {
  __builtin_amdgcn_global_load_lds(
      (__attribute__((address_space(1))) void*)(void*)g,
      (__attribute__((address_space(3))) void*)l, 16, 0, 0);
}

// ---------------------------------------------------------------------------
// f32 -> bf16 conversion (weights only), 8 elems/thread
// ---------------------------------------------------------------------------
__global__ __launch_bounds__(256) void cvt_kernel(const float* __restrict__ src,
                                                  uint16_t* __restrict__ dst, int n8) {
  int i = blockIdx.x * blockDim.x + threadIdx.x;
  if (i >= n8) return;
  const float4* s = (const float4*)src;
  float4 a = s[2 * i];
  float4 b = s[2 * i + 1];
  uint4 pk;
  pk.x = pack2(a.x, a.y);
  pk.y = pack2(a.z, a.w);
  pk.z = pack2(b.x, b.y);
  pk.w = pack2(b.z, b.w);
  ((uint4*)dst)[i] = pk;
}

// ---------------------------------------------------------------------------
// NT GEMM: C[m][n] = sum_k A[m][k] * B[n][k]  (+bias), bf16 MFMA 16x16x32
// Tile 128x128, BK=32, 256 threads = 4 waves, each wave 64x64 (4x4 subtiles).
// LDS tiles stored as 16B chunks with XOR swizzle: physical chunk of logical
// k-chunk lc at row m is pc = lc ^ ((m>>1)&3). 2-way-or-less bank aliasing on
// ds_read_b128 (free per m136); global_load_lds stays lane-contiguous because
// the swizzle is applied to the *source* address.
// ---------------------------------------------------------------------------
template <bool A_F32, bool OUT_BF16>
__global__ __launch_bounds__(256) void gemm_bt(const void* __restrict__ Ap,
                                               const uint16_t* __restrict__ Bp,
                                               void* __restrict__ Cp,
                                               const float* __restrict__ bias,
                                               int M, int N, int K) {
  constexpr int BM = 128, BN = 128, BK = 32;
  __shared__ __align__(16) uint16_t Alds[BM * BK];
  __shared__ __align__(16) uint16_t Blds[BN * BK];

  const int tid = threadIdx.x;
  const int wave = tid >> 6;
  const int lane = tid & 63;
  const int quad = lane >> 4;
  const int l16 = lane & 15;
  const int wm = (wave >> 1) * 64;
  const int wn = (wave & 1) * 64;
  const int bm0 = blockIdx.x * BM;
  const int bn0 = blockIdx.y * BN;

  f32x4 acc[4][4];
#pragma unroll
  for (int i = 0; i < 4; ++i)
#pragma unroll
    for (int j = 0; j < 4; ++j) acc[i][j] = (f32x4){0.f, 0.f, 0.f, 0.f};

  // B tile async staging: chunk p = wave*128 + j*64 + lane lands at LDS byte p*16
  const uint16_t* bsrc[2];
  uint16_t* bdst[2];
#pragma unroll
  for (int j = 0; j < 2; ++j) {
    const int p = wave * 128 + j * 64 + lane;
    const int m = p >> 2;
    const int lc = (p & 3) ^ ((m >> 1) & 3);
    bsrc[j] = Bp + (size_t)(bn0 + m) * K + lc * 8;
    bdst[j] = &Blds[(wave * 128 + j * 64) * 8];  // wave-uniform base
  }

  const float* asrcf[2];
  int adst_f[2];
  const uint16_t* asrc16[2];
  uint16_t* adst16[2];
  if constexpr (A_F32) {
    // register staging with cvt: thread handles chunks tid and tid+256
#pragma unroll
    for (int c = 0; c < 2; ++c) {
      const int p = tid + c * 256;
      const int m = p >> 2;
      const int lc = (p & 3) ^ ((m >> 1) & 3);
      asrcf[c] = (const float*)Ap + (size_t)(bm0 + m) * K + lc * 8;
      adst_f[c] = p * 8;  // ushort index; byte p*16
    }
  } else {
#pragma unroll
    for (int j = 0; j < 2; ++j) {
      const int p = wave * 128 + j * 64 + lane;
      const int m = p >> 2;
      const int lc = (p & 3) ^ ((m >> 1) & 3);
      asrc16[j] = (const uint16_t*)Ap + (size_t)(bm0 + m) * K + lc * 8;
      adst16[j] = &Alds[(wave * 128 + j * 64) * 8];
    }
  }

  for (int k0 = 0; k0 < K; k0 += BK) {
#pragma unroll
    for (int j = 0; j < 2; ++j) gload_lds16(bsrc[j] + k0, bdst[j]);
    if constexpr (!A_F32) {
#pragma unroll
      for (int j = 0; j < 2; ++j) gload_lds16(asrc16[j] + k0, adst16[j]);
    } else {
#pragma unroll
      for (int c = 0; c < 2; ++c) {
        const float4* g = (const float4*)(asrcf[c] + k0);
        float4 x = g[0];
        float4 y = g[1];
        uint4 pk;
        pk.x = pack2(x.x, x.y);
        pk.y = pack2(x.z, x.w);
        pk.z = pack2(y.x, y.y);
        pk.w = pack2(y.z, y.w);
        *(uint4*)&Alds[adst_f[c]] = pk;
      }
    }
    __syncthreads();

    s16x8 af[4], bfv[4];
#pragma unroll
    for (int s = 0; s < 4; ++s) {
      const int ml = wm + s * 16 + l16;
      const int ca = ml * 4 + (quad ^ ((ml >> 1) & 3));
      af[s] = *(const s16x8*)&Alds[ca * 8];
      const int nl = wn + s * 16 + l16;
      const int cb = nl * 4 + (quad ^ ((nl >> 1) & 3));
      bfv[s] = *(const s16x8*)&Blds[cb * 8];
    }
#pragma unroll
    for (int sm = 0; sm < 4; ++sm)
#pragma unroll
      for (int sn = 0; sn < 4; ++sn)
        acc[sm][sn] =
            __builtin_amdgcn_mfma_f32_16x16x32_bf16(af[sm], bfv[sn], acc[sm][sn], 0, 0, 0);
    __syncthreads();
  }

  // epilogue: C/D layout col = lane&15, row = quad*4 + r (m89-verified)
#pragma unroll
  for (int sm = 0; sm < 4; ++sm) {
    const int mrow = bm0 + wm + sm * 16 + quad * 4;
#pragma unroll
    for (int sn = 0; sn < 4; ++sn) {
      const int ncol = bn0 + wn + sn * 16 + l16;
      if constexpr (OUT_BF16) {
        uint16_t* Cb = (uint16_t*)Cp;
#pragma unroll
        for (int r = 0; r < 4; ++r) Cb[(size_t)(mrow + r) * N + ncol] = f2bf(acc[sm][sn][r]);
      } else {
        float* Cf = (float*)Cp;
        const float bv = bias[ncol];
#pragma unroll
        for (int r = 0; r < 4; ++r) Cf[(size_t)(mrow + r) * N + ncol] = acc[sm][sn][r] + bv;
      }
    }
  }
}

// ---------------------------------------------------------------------------
// Per-token head-mixing attention. One block (256 thr) per token (b,n).
// s[h][g] = SCALE * sum_d q[h][d]k[g][d]; softmax over g; x[h][d]=sum_g a*v.
// Stores x into the "buggy reshape" position:
//   X2[b, h*128 + n/16, (n%16)*64 + d]
// ---------------------------------------------------------------------------
__global__ __launch_bounds__(256) void attn_kernel(const uint16_t* __restrict__ qb,
                                                   const uint16_t* __restrict__ kb,
                                                   const uint16_t* __restrict__ vb,
                                                   uint16_t* __restrict__ x2b) {
  __shared__ float qs[16 * 65];
  __shared__ float ks[16 * 65];
  __shared__ float vs[16 * 65];
  __shared__ float sb[16 * 17];

  const int t = threadIdx.x;
  const int token = blockIdx.x;
  const int b = token >> 11;
  const int n = token & 2047;
  const size_t base = (size_t)token * 1024;

  {
    const int i = t * 4;
    const int hh = i >> 6;
    const int dd = i & 63;
    const int o = hh * 65 + dd;
    uint2 qa = *(const uint2*)(qb + base + i);
    uint2 ka = *(const uint2*)(kb + base + i);
    uint2 va = *(const uint2*)(vb + base + i);
    qs[o + 0] = bf2f((uint16_t)(qa.x & 0xffff));
    qs[o + 1] = bf2f((uint16_t)(qa.x >> 16));
    qs[o + 2] = bf2f((uint16_t)(qa.y & 0xffff));
    qs[o + 3] = bf2f((uint16_t)(qa.y >> 16));
    ks[o + 0] = bf2f((uint16_t)(ka.x & 0xffff));
    ks[o + 1] = bf2f((uint16_t)(ka.x >> 16));
    ks[o + 2] = bf2f((uint16_t)(ka.y & 0xffff));
    ks[o + 3] = bf2f((uint16_t)(ka.y >> 16));
    vs[o + 0] = bf2f((uint16_t)(va.x & 0xffff));
    vs[o + 1] = bf2f((uint16_t)(va.x >> 16));
    vs[o + 2] = bf2f((uint16_t)(va.y & 0xffff));
    vs[o + 3] = bf2f((uint16_t)(va.y >> 16));
  }
  __syncthreads();

  const int h = t >> 4;
  const int g = t & 15;
  {
    float a = 0.f;
#pragma unroll
    for (int d = 0; d < 64; ++d) a += qs[h * 65 + d] * ks[g * 65 + d];
    sb[h * 17 + g] = a * 0.125f;  // SCALE = 64^-0.5
  }
  __syncthreads();
  if (t < 16) {
    float mx = -1e30f;
    for (int j = 0; j < 16; ++j) mx = fmaxf(mx, sb[t * 17 + j]);
    float ssum = 0.f;
    for (int j = 0; j < 16; ++j) {
      float e = __expf(sb[t * 17 + j] - mx);
      sb[t * 17 + j] = e;
      ssum += e;
    }
    float inv = 1.f / ssum;
    for (int j = 0; j < 16; ++j) sb[t * 17 + j] *= inv;
  }
  __syncthreads();
  {
    const int d0 = (t & 15) * 4;
    float x0 = 0.f, x1 = 0.f, x2 = 0.f, x3 = 0.f;
#pragma unroll
    for (int gg = 0; gg < 16; ++gg) {
      const float a = sb[h * 17 + gg];
      const float* vr = &vs[gg * 65 + d0];
      x0 += a * vr[0];
      x1 += a * vr[1];
      x2 += a * vr[2];
      x3 += a * vr[3];
    }
    const int i2 = h * 128 + (n >> 4);
    const int j2 = (n & 15) * 64 + d0;
    uint2 pk;
    pk.x = pack2(x0, x1);
    pk.y = pack2(x2, x3);
    *(uint2*)&x2b[(size_t)b * (2048 * 1024) + (size_t)i2 * 1024 + j2] = pk;
  }
}

// ---------------------------------------------------------------------------
extern "C" void kernel_launch(void* const* d_in, const int* in_sizes, int n_in,
                              void* d_out, int out_size, void* d_ws, size_t ws_size,
                              hipStream_t stream) {
  const float* query = (const float*)d_in[0];
  const float* key = (const float*)d_in[1];
  const float* value = (const float*)d_in[2];
  // d_in[3]=xpos, d_in[4]=ypos unused (rope is None)
  const float* Wq = (const float*)d_in[5];
  const float* Wk = (const float*)d_in[6];
  const float* Wv = (const float*)d_in[7];
  const float* Wp = (const float*)d_in[8];
  const float* bp = (const float*)d_in[9];
  float* out = (float*)d_out;

  const int C = 1024;
  const int M = 8 * 2048;  // 16384 tokens
  const size_t MC = (size_t)M * C;

  // workspace layout (bf16 = uint16): q,k,v,x2 (4*32 MiB) + 4 weights (8 MiB) = 136 MiB
  uint16_t* ws = (uint16_t*)d_ws;
  uint16_t* qb = ws;
  uint16_t* kb = qb + MC;
  uint16_t* vb = kb + MC;
  uint16_t* x2b = vb + MC;
  uint16_t* wqb = x2b + MC;
  uint16_t* wkb = wqb + (size_t)C * C;
  uint16_t* wvb = wkb + (size_t)C * C;
  uint16_t* wpb = wvb + (size_t)C * C;

  // weights f32 -> bf16
  {
    const int n8 = C * C / 8;
    dim3 g((n8 + 255) / 256), blk(256);
    cvt_kernel<<<g, blk, 0, stream>>>(Wq, wqb, n8);
    cvt_kernel<<<g, blk, 0, stream>>>(Wk, wkb, n8);
    cvt_kernel<<<g, blk, 0, stream>>>(Wv, wvb, n8);
    cvt_kernel<<<g, blk, 0, stream>>>(Wp, wpb, n8);
  }

  dim3 gg(M / 128, C / 128), blk(256);
  gemm_bt<true, true><<<gg, blk, 0, stream>>>(query, wqb, qb, nullptr, M, C, C);
  gemm_bt<true, true><<<gg, blk, 0, stream>>>(key, wkb, kb, nullptr, M, C, C);
  gemm_bt<true, true><<<gg, blk, 0, stream>>>(value, wvb, vb, nullptr, M, C, C);

  attn_kernel<<<dim3(M), dim3(256), 0, stream>>>(qb, kb, vb, x2b);

  gemm_bt<false, false><<<gg, blk, 0, stream>>>(x2b, wpb, out, bp, M, C, C);
}

// Round 2
// 511.920 us; speedup vs baseline: 1.0787x; 1.0787x over previous
//
#include <hip/hip_runtime.h>
#include <stdint.h>

#define DEV __device__ __forceinline__

using f32x4 = __attribute__((ext_vector_type(4))) float;
using s16x8 = __attribute__((ext_vector_type(8))) short;

DEV uint16_t f2bf(float f) {
  union { float f; uint32_t u; } v; v.f = f;
  uint32_t r = v.u + 0x7fffu + ((v.u >> 16) & 1u);  // round-to-nearest-even
  return (uint16_t)(r >> 16);
}
DEV float bf2f(uint16_t h) {
  union { uint32_t u; float f; } v; v.u = (uint32_t)h << 16;
  return v.f;
}
DEV uint32_t pack2(float a, float b) {
  return (uint32_t)f2bf(a) | ((uint32_t)f2bf(b) << 16);
}

// async global->LDS, 16B per lane; LDS dest = wave-uniform base + lane*16
DEV void gload_lds16(const void* g, void* l) {
  __builtin_amdgcn_global_load_lds(
      (__attribute__((address_space(1))) void*)(void*)g,
      (__attribute__((address_space(3))) void*)l, 16, 0, 0);
}

// ---------------------------------------------------------------------------
// f32 -> bf16 weights conversion, all 4 weights in one launch.
// Regions of n8=131072 chunks each: 0=Wq,1=Wk,2=Wv -> wqkv rows; 3=Wp -> wpb.
// ---------------------------------------------------------------------------
__global__ __launch_bounds__(256) void cvt_w_kernel(const float* __restrict__ Wq,
                                                    const float* __restrict__ Wk,
                                                    const float* __restrict__ Wv,
                                                    const float* __restrict__ Wp,
                                                    uint16_t* __restrict__ wqb,
                                                    uint16_t* __restrict__ wkb,
                                                    uint16_t* __restrict__ wvb,
                                                    uint16_t* __restrict__ wpb) {
  const int idx = blockIdx.x * blockDim.x + threadIdx.x;  // 4*131072 total
  const int region = idx >> 17;
  const int i = idx & 131071;
  const float* src = region == 0 ? Wq : region == 1 ? Wk : region == 2 ? Wv : Wp;
  uint16_t* dst = region == 0 ? wqb : region == 1 ? wkb : region == 2 ? wvb : wpb;
  const float4* s = (const float4*)src;
  float4 a = s[2 * i];
  float4 b = s[2 * i + 1];
  uint4 pk;
  pk.x = pack2(a.x, a.y);
  pk.y = pack2(a.z, a.w);
  pk.z = pack2(b.x, b.y);
  pk.w = pack2(b.z, b.w);
  ((uint4*)dst)[i] = pk;
}

// ---------------------------------------------------------------------------
// NT GEMM: C[m][n] = sum_k A[m][k] * B[n][k]  (+bias), bf16 MFMA 16x16x32
// Tile 128x128, BK=32, 256 threads = 4 waves, each wave 64x64 (4x4 subtiles).
// blockIdx.z selects one of up to 3 independent (A,B,C) problems (QKV batch).
// LDS 16B-chunk XOR swizzle pc = lc ^ ((m>>1)&3): <=2-way aliasing (free).
// A_F32 path: A staged via registers with f32->bf16 cvt, double-buffered so
// the next iter's global loads ride the barrier's vmcnt(0) drain for free.
// ---------------------------------------------------------------------------
struct GemmBatch {
  const void* A[3];
  const uint16_t* B[3];
  void* C[3];
};

template <bool A_F32, bool OUT_BF16>
__global__ __launch_bounds__(256) void gemm_bt(GemmBatch gb,
                                               const float* __restrict__ bias,
                                               int M, int N, int K) {
  constexpr int BM = 128, BN = 128, BK = 32;
  __shared__ __align__(16) uint16_t Alds[BM * BK];
  __shared__ __align__(16) uint16_t Blds[BN * BK];

  const int z = blockIdx.z;
  const void* __restrict__ Ap = gb.A[z];
  const uint16_t* __restrict__ Bp = gb.B[z];
  void* __restrict__ Cp = gb.C[z];

  const int tid = threadIdx.x;
  const int wave = tid >> 6;
  const int lane = tid & 63;
  const int quad = lane >> 4;
  const int l16 = lane & 15;
  const int wm = (wave >> 1) * 64;
  const int wn = (wave & 1) * 64;
  const int bm0 = blockIdx.x * BM;
  const int bn0 = blockIdx.y * BN;

  f32x4 acc[4][4];
#pragma unroll
  for (int i = 0; i < 4; ++i)
#pragma unroll
    for (int j = 0; j < 4; ++j) acc[i][j] = (f32x4){0.f, 0.f, 0.f, 0.f};

  // B tile async staging: chunk p = wave*128 + j*64 + lane lands at LDS byte p*16
  const uint16_t* bsrc[2];
  uint16_t* bdst[2];
#pragma unroll
  for (int j = 0; j < 2; ++j) {
    const int p = wave * 128 + j * 64 + lane;
    const int m = p >> 2;
    const int lc = (p & 3) ^ ((m >> 1) & 3);
    bsrc[j] = Bp + (size_t)(bn0 + m) * K + lc * 8;
    bdst[j] = &Blds[(wave * 128 + j * 64) * 8];  // wave-uniform base
  }

  const float* asrcf[2];
  int adst_f[2];
  const uint16_t* asrc16[2];
  uint16_t* adst16[2];
  float4 cur[2][2], nxt[2][2];
  if constexpr (A_F32) {
    // register staging with cvt: thread handles chunks tid and tid+256
#pragma unroll
    for (int c = 0; c < 2; ++c) {
      const int p = tid + c * 256;
      const int m = p >> 2;
      const int lc = (p & 3) ^ ((m >> 1) & 3);
      asrcf[c] = (const float*)Ap + (size_t)(bm0 + m) * K + lc * 8;
      adst_f[c] = p * 8;  // ushort index; byte p*16
    }
    // prologue: load iter-0 A regs
#pragma unroll
    for (int c = 0; c < 2; ++c) {
      const float4* g = (const float4*)asrcf[c];
      cur[c][0] = g[0];
      cur[c][1] = g[1];
    }
  } else {
#pragma unroll
    for (int j = 0; j < 2; ++j) {
      const int p = wave * 128 + j * 64 + lane;
      const int m = p >> 2;
      const int lc = (p & 3) ^ ((m >> 1) & 3);
      asrc16[j] = (const uint16_t*)Ap + (size_t)(bm0 + m) * K + lc * 8;
      adst16[j] = &Alds[(wave * 128 + j * 64) * 8];
    }
  }

  for (int k0 = 0; k0 < K; k0 += BK) {
    // issue async B staging first (stays in flight through the VALU below)
#pragma unroll
    for (int j = 0; j < 2; ++j) gload_lds16(bsrc[j] + k0, bdst[j]);
    if constexpr (!A_F32) {
#pragma unroll
      for (int j = 0; j < 2; ++j) gload_lds16(asrc16[j] + k0, adst16[j]);
    } else {
      // pack current A regs (loaded >=1 iter ago) -> LDS
#pragma unroll
      for (int c = 0; c < 2; ++c) {
        uint4 pk;
        pk.x = pack2(cur[c][0].x, cur[c][0].y);
        pk.y = pack2(cur[c][0].z, cur[c][0].w);
        pk.z = pack2(cur[c][1].x, cur[c][1].y);
        pk.w = pack2(cur[c][1].z, cur[c][1].w);
        *(uint4*)&Alds[adst_f[c]] = pk;
      }
      // prefetch next iter's A f32 into regs; the barrier's vmcnt(0) drain
      // (needed for B's global_load_lds anyway) absorbs this latency.
      if (k0 + BK < K) {
#pragma unroll
        for (int c = 0; c < 2; ++c) {
          const float4* g = (const float4*)(asrcf[c] + k0 + BK);
          nxt[c][0] = g[0];
          nxt[c][1] = g[1];
        }
      }
    }
    __syncthreads();

    s16x8 af[4], bfv[4];
#pragma unroll
    for (int s = 0; s < 4; ++s) {
      const int ml = wm + s * 16 + l16;
      const int ca = ml * 4 + (quad ^ ((ml >> 1) & 3));
      af[s] = *(const s16x8*)&Alds[ca * 8];
      const int nl = wn + s * 16 + l16;
      const int cb = nl * 4 + (quad ^ ((nl >> 1) & 3));
      bfv[s] = *(const s16x8*)&Blds[cb * 8];
    }
#pragma unroll
    for (int sm = 0; sm < 4; ++sm)
#pragma unroll
      for (int sn = 0; sn < 4; ++sn)
        acc[sm][sn] =
            __builtin_amdgcn_mfma_f32_16x16x32_bf16(af[sm], bfv[sn], acc[sm][sn], 0, 0, 0);
    __syncthreads();

    if constexpr (A_F32) {
#pragma unroll
      for (int c = 0; c < 2; ++c) {
        cur[c][0] = nxt[c][0];
        cur[c][1] = nxt[c][1];
      }
    }
  }

  // epilogue: C/D layout col = lane&15, row = quad*4 + r (m89-verified)
#pragma unroll
  for (int sm = 0; sm < 4; ++sm) {
    const int mrow = bm0 + wm + sm * 16 + quad * 4;
#pragma unroll
    for (int sn = 0; sn < 4; ++sn) {
      const int ncol = bn0 + wn + sn * 16 + l16;
      if constexpr (OUT_BF16) {
        uint16_t* Cb = (uint16_t*)Cp;
#pragma unroll
        for (int r = 0; r < 4; ++r) Cb[(size_t)(mrow + r) * N + ncol] = f2bf(acc[sm][sn][r]);
      } else {
        float* Cf = (float*)Cp;
        const float bv = bias[ncol];
#pragma unroll
        for (int r = 0; r < 4; ++r) Cf[(size_t)(mrow + r) * N + ncol] = acc[sm][sn][r] + bv;
      }
    }
  }
}

// ---------------------------------------------------------------------------
// Per-token head-mixing attention. One block (256 thr) per token (b,n).
// s[h][g] = SCALE * sum_d q[h][d]k[g][d]; softmax over g; x[h][d]=sum_g a*v.
// Stores x into the "buggy reshape" position:
//   X2[b, h*128 + n/16, (n%16)*64 + d]
// ---------------------------------------------------------------------------
__global__ __launch_bounds__(256) void attn_kernel(const uint16_t* __restrict__ qb,
                                                   const uint16_t* __restrict__ kb,
                                                   const uint16_t* __restrict__ vb,
                                                   uint16_t* __restrict__ x2b) {
  __shared__ float qs[16 * 65];
  __shared__ float ks[16 * 65];
  __shared__ float vs[16 * 65];
  __shared__ float sb[16 * 17];

  const int t = threadIdx.x;
  const int token = blockIdx.x;
  const int b = token >> 11;
  const int n = token & 2047;
  const size_t base = (size_t)token * 1024;

  {
    const int i = t * 4;
    const int hh = i >> 6;
    const int dd = i & 63;
    const int o = hh * 65 + dd;
    uint2 qa = *(const uint2*)(qb + base + i);
    uint2 ka = *(const uint2*)(kb + base + i);
    uint2 va = *(const uint2*)(vb + base + i);
    qs[o + 0] = bf2f((uint16_t)(qa.x & 0xffff));
    qs[o + 1] = bf2f((uint16_t)(qa.x >> 16));
    qs[o + 2] = bf2f((uint16_t)(qa.y & 0xffff));
    qs[o + 3] = bf2f((uint16_t)(qa.y >> 16));
    ks[o + 0] = bf2f((uint16_t)(ka.x & 0xffff));
    ks[o + 1] = bf2f((uint16_t)(ka.x >> 16));
    ks[o + 2] = bf2f((uint16_t)(ka.y & 0xffff));
    ks[o + 3] = bf2f((uint16_t)(ka.y >> 16));
    vs[o + 0] = bf2f((uint16_t)(va.x & 0xffff));
    vs[o + 1] = bf2f((uint16_t)(va.x >> 16));
    vs[o + 2] = bf2f((uint16_t)(va.y & 0xffff));
    vs[o + 3] = bf2f((uint16_t)(va.y >> 16));
  }
  __syncthreads();

  const int h = t >> 4;
  const int g = t & 15;
  {
    float a = 0.f;
#pragma unroll
    for (int d = 0; d < 64; ++d) a += qs[h * 65 + d] * ks[g * 65 + d];
    sb[h * 17 + g] = a * 0.125f;  // SCALE = 64^-0.5
  }
  __syncthreads();
  if (t < 16) {
    float mx = -1e30f;
    for (int j = 0; j < 16; ++j) mx = fmaxf(mx, sb[t * 17 + j]);
    float ssum = 0.f;
    for (int j = 0; j < 16; ++j) {
      float e = __expf(sb[t * 17 + j] - mx);
      sb[t * 17 + j] = e;
      ssum += e;
    }
    float inv = 1.f / ssum;
    for (int j = 0; j < 16; ++j) sb[t * 17 + j] *= inv;
  }
  __syncthreads();
  {
    const int d0 = (t & 15) * 4;
    float x0 = 0.f, x1 = 0.f, x2 = 0.f, x3 = 0.f;
#pragma unroll
    for (int gg = 0; gg < 16; ++gg) {
      const float a = sb[h * 17 + gg];
      const float* vr = &vs[gg * 65 + d0];
      x0 += a * vr[0];
      x1 += a * vr[1];
      x2 += a * vr[2];
      x3 += a * vr[3];
    }
    const int i2 = h * 128 + (n >> 4);
    const int j2 = (n & 15) * 64 + d0;
    uint2 pk;
    pk.x = pack2(x0, x1);
    pk.y = pack2(x2, x3);
    *(uint2*)&x2b[(size_t)b * (2048 * 1024) + (size_t)i2 * 1024 + j2] = pk;
  }
}

// ---------------------------------------------------------------------------
extern "C" void kernel_launch(void* const* d_in, const int* in_sizes, int n_in,
                              void* d_out, int out_size, void* d_ws, size_t ws_size,
                              hipStream_t stream) {
  const float* query = (const float*)d_in[0];
  const float* key = (const float*)d_in[1];
  const float* value = (const float*)d_in[2];
  // d_in[3]=xpos, d_in[4]=ypos unused (rope is None)
  const float* Wq = (const float*)d_in[5];
  const float* Wk = (const float*)d_in[6];
  const float* Wv = (const float*)d_in[7];
  const float* Wp = (const float*)d_in[8];
  const float* bp = (const float*)d_in[9];
  float* out = (float*)d_out;

  const int C = 1024;
  const int M = 8 * 2048;  // 16384 tokens
  const size_t MC = (size_t)M * C;

  // workspace layout (bf16 = uint16): q,k,v,x2 (4*32 MiB) + 4 weights (8 MiB) = 136 MiB
  uint16_t* ws = (uint16_t*)d_ws;
  uint16_t* qb = ws;
  uint16_t* kb = qb + MC;
  uint16_t* vb = kb + MC;
  uint16_t* x2b = vb + MC;
  uint16_t* wqb = x2b + MC;
  uint16_t* wkb = wqb + (size_t)C * C;
  uint16_t* wvb = wkb + (size_t)C * C;
  uint16_t* wpb = wvb + (size_t)C * C;

  // all 4 weight conversions in one launch: 4 * 131072 chunk-threads
  cvt_w_kernel<<<dim3(4 * 131072 / 256), dim3(256), 0, stream>>>(Wq, Wk, Wv, Wp, wqb, wkb,
                                                                 wvb, wpb);

  // batched QKV projections: blockIdx.z picks the problem
  GemmBatch qkv;
  qkv.A[0] = query;  qkv.B[0] = wqb;  qkv.C[0] = qb;
  qkv.A[1] = key;    qkv.B[1] = wkb;  qkv.C[1] = kb;
  qkv.A[2] = value;  qkv.B[2] = wvb;  qkv.C[2] = vb;
  gemm_bt<true, true><<<dim3(M / 128, C / 128, 3), dim3(256), 0, stream>>>(qkv, nullptr, M,
                                                                           C, C);

  attn_kernel<<<dim3(M), dim3(256), 0, stream>>>(qb, kb, vb, x2b);

  GemmBatch fin;
  fin.A[0] = x2b;  fin.B[0] = wpb;  fin.C[0] = out;
  fin.A[1] = x2b;  fin.B[1] = wpb;  fin.C[1] = out;
  fin.A[2] = x2b;  fin.B[2] = wpb;  fin.C[2] = out;
  gemm_bt<false, false><<<dim3(M / 128, C / 128, 1), dim3(256), 0, stream>>>(fin, bp, M, C,
                                                                             C);
}

// Round 3
// 495.115 us; speedup vs baseline: 1.1153x; 1.0339x over previous
//
#include <hip/hip_runtime.h>
#include <stdint.h>

#define DEV __device__ __forceinline__

using f32x4 = __attribute__((ext_vector_type(4))) float;
using s16x8 = __attribute__((ext_vector_type(8))) short;

DEV uint16_t f2bf(float f) {
  union { float f; uint32_t u; } v; v.f = f;
  uint32_t r = v.u + 0x7fffu + ((v.u >> 16) & 1u);  // round-to-nearest-even
  return (uint16_t)(r >> 16);
}
DEV uint32_t pack2(float a, float b) {
  return (uint32_t)f2bf(a) | ((uint32_t)f2bf(b) << 16);
}

// async global->LDS, 16B per lane; LDS dest = wave-uniform base + lane*16
DEV void gload_lds16(const void* g, void* l) {
  __builtin_amdgcn_global_load_lds(
      (__attribute__((address_space(1))) void*)(void*)g,
      (__attribute__((address_space(3))) void*)l, 16, 0, 0);
}

// ---------------------------------------------------------------------------
// f32 -> bf16 weights conversion, all 4 weights in one launch.
// ---------------------------------------------------------------------------
__global__ __launch_bounds__(256) void cvt_w_kernel(const float* __restrict__ Wq,
                                                    const float* __restrict__ Wk,
                                                    const float* __restrict__ Wv,
                                                    const float* __restrict__ Wp,
                                                    uint16_t* __restrict__ wqb,
                                                    uint16_t* __restrict__ wkb,
                                                    uint16_t* __restrict__ wvb,
                                                    uint16_t* __restrict__ wpb) {
  const int idx = blockIdx.x * blockDim.x + threadIdx.x;  // 4*131072 total
  const int region = idx >> 17;
  const int i = idx & 131071;
  const float* src = region == 0 ? Wq : region == 1 ? Wk : region == 2 ? Wv : Wp;
  uint16_t* dst = region == 0 ? wqb : region == 1 ? wkb : region == 2 ? wvb : wpb;
  const float4* s = (const float4*)src;
  float4 a = s[2 * i];
  float4 b = s[2 * i + 1];
  uint4 pk;
  pk.x = pack2(a.x, a.y);
  pk.y = pack2(a.z, a.w);
  pk.z = pack2(b.x, b.y);
  pk.w = pack2(b.z, b.w);
  ((uint4*)dst)[i] = pk;
}

// ---------------------------------------------------------------------------
// NT GEMM: C[m][n] = sum_k A[m][k] * B[n][k]  (+bias), bf16 MFMA 16x16x32
// Tile 128x128, BK=32, 256 threads = 4 waves, each wave 64x64 (4x4 subtiles).
// Grid is (bn, bm, problem) -- bn FASTEST so co-resident blocks share one A
// row-tile across all 8 bn (A fetched once; B fully L2-resident).
// LDS 16B-chunk XOR swizzle pc = lc ^ ((m>>1)&3): <=2-way aliasing (free).
// ---------------------------------------------------------------------------
struct GemmBatch {
  const void* A[3];
  const uint16_t* B[3];
  void* C[3];
};

template <bool A_F32, bool OUT_BF16>
__global__ __launch_bounds__(256) void gemm_bt(GemmBatch gb,
                                               const float* __restrict__ bias,
                                               int M, int N, int K) {
  constexpr int BM = 128, BN = 128, BK = 32;
  __shared__ __align__(16) uint16_t Alds[BM * BK];
  __shared__ __align__(16) uint16_t Blds[BN * BK];

  const int z = blockIdx.z;
  const void* __restrict__ Ap = gb.A[z];
  const uint16_t* __restrict__ Bp = gb.B[z];
  void* __restrict__ Cp = gb.C[z];

  const int tid = threadIdx.x;
  const int wave = tid >> 6;
  const int lane = tid & 63;
  const int quad = lane >> 4;
  const int l16 = lane & 15;
  const int wm = (wave >> 1) * 64;
  const int wn = (wave & 1) * 64;
  const int bm0 = blockIdx.y * BM;  // bn fastest: x = N-tile, y = M-tile
  const int bn0 = blockIdx.x * BN;

  f32x4 acc[4][4];
#pragma unroll
  for (int i = 0; i < 4; ++i)
#pragma unroll
    for (int j = 0; j < 4; ++j) acc[i][j] = (f32x4){0.f, 0.f, 0.f, 0.f};

  // B tile async staging: chunk p = wave*128 + j*64 + lane lands at LDS byte p*16
  const uint16_t* bsrc[2];
  uint16_t* bdst[2];
#pragma unroll
  for (int j = 0; j < 2; ++j) {
    const int p = wave * 128 + j * 64 + lane;
    const int m = p >> 2;
    const int lc = (p & 3) ^ ((m >> 1) & 3);
    bsrc[j] = Bp + (size_t)(bn0 + m) * K + lc * 8;
    bdst[j] = &Blds[(wave * 128 + j * 64) * 8];  // wave-uniform base
  }

  const float* asrcf[2];
  int adst_f[2];
  const uint16_t* asrc16[2];
  uint16_t* adst16[2];
  float4 cur[2][2], nxt[2][2];
  if constexpr (A_F32) {
    // register staging with cvt: thread handles chunks tid and tid+256
#pragma unroll
    for (int c = 0; c < 2; ++c) {
      const int p = tid + c * 256;
      const int m = p >> 2;
      const int lc = (p & 3) ^ ((m >> 1) & 3);
      asrcf[c] = (const float*)Ap + (size_t)(bm0 + m) * K + lc * 8;
      adst_f[c] = p * 8;  // ushort index; byte p*16
    }
    // prologue: load iter-0 A regs
#pragma unroll
    for (int c = 0; c < 2; ++c) {
      const float4* g = (const float4*)asrcf[c];
      cur[c][0] = g[0];
      cur[c][1] = g[1];
    }
  } else {
#pragma unroll
    for (int j = 0; j < 2; ++j) {
      const int p = wave * 128 + j * 64 + lane;
      const int m = p >> 2;
      const int lc = (p & 3) ^ ((m >> 1) & 3);
      asrc16[j] = (const uint16_t*)Ap + (size_t)(bm0 + m) * K + lc * 8;
      adst16[j] = &Alds[(wave * 128 + j * 64) * 8];
    }
  }

  for (int k0 = 0; k0 < K; k0 += BK) {
    // issue async B staging first (stays in flight through the VALU below)
#pragma unroll
    for (int j = 0; j < 2; ++j) gload_lds16(bsrc[j] + k0, bdst[j]);
    if constexpr (!A_F32) {
#pragma unroll
      for (int j = 0; j < 2; ++j) gload_lds16(asrc16[j] + k0, adst16[j]);
    } else {
      // pack current A regs (loaded >=1 iter ago) -> LDS
#pragma unroll
      for (int c = 0; c < 2; ++c) {
        uint4 pk;
        pk.x = pack2(cur[c][0].x, cur[c][0].y);
        pk.y = pack2(cur[c][0].z, cur[c][0].w);
        pk.z = pack2(cur[c][1].x, cur[c][1].y);
        pk.w = pack2(cur[c][1].z, cur[c][1].w);
        *(uint4*)&Alds[adst_f[c]] = pk;
      }
      // prefetch next iter's A f32 into regs; the barrier's vmcnt(0) drain
      // (needed for B's global_load_lds anyway) absorbs this latency.
      if (k0 + BK < K) {
#pragma unroll
        for (int c = 0; c < 2; ++c) {
          const float4* g = (const float4*)(asrcf[c] + k0 + BK);
          nxt[c][0] = g[0];
          nxt[c][1] = g[1];
        }
      }
    }
    __syncthreads();

    s16x8 af[4], bfv[4];
#pragma unroll
    for (int s = 0; s < 4; ++s) {
      const int ml = wm + s * 16 + l16;
      const int ca = ml * 4 + (quad ^ ((ml >> 1) & 3));
      af[s] = *(const s16x8*)&Alds[ca * 8];
      const int nl = wn + s * 16 + l16;
      const int cb = nl * 4 + (quad ^ ((nl >> 1) & 3));
      bfv[s] = *(const s16x8*)&Blds[cb * 8];
    }
#pragma unroll
    for (int sm = 0; sm < 4; ++sm)
#pragma unroll
      for (int sn = 0; sn < 4; ++sn)
        acc[sm][sn] =
            __builtin_amdgcn_mfma_f32_16x16x32_bf16(af[sm], bfv[sn], acc[sm][sn], 0, 0, 0);
    __syncthreads();

    if constexpr (A_F32) {
#pragma unroll
      for (int c = 0; c < 2; ++c) {
        cur[c][0] = nxt[c][0];
        cur[c][1] = nxt[c][1];
      }
    }
  }

  // epilogue: C/D layout col = lane&15, row = quad*4 + r (m89-verified)
#pragma unroll
  for (int sm = 0; sm < 4; ++sm) {
    const int mrow = bm0 + wm + sm * 16 + quad * 4;
#pragma unroll
    for (int sn = 0; sn < 4; ++sn) {
      const int ncol = bn0 + wn + sn * 16 + l16;
      if constexpr (OUT_BF16) {
        uint16_t* Cb = (uint16_t*)Cp;
#pragma unroll
        for (int r = 0; r < 4; ++r) Cb[(size_t)(mrow + r) * N + ncol] = f2bf(acc[sm][sn][r]);
      } else {
        float* Cf = (float*)Cp;
        const float bv = bias[ncol];
#pragma unroll
        for (int r = 0; r < 4; ++r) Cf[(size_t)(mrow + r) * N + ncol] = acc[sm][sn][r] + bv;
      }
    }
  }
}

// ---------------------------------------------------------------------------
// MFMA attention: one WAVE per token. S = Q·K^T via 2x mfma_16x16x32_bf16
// (A-frag = Q[l16][quad*8+j], B-frag = K[l16][quad*8+j] -- the exact layout
// the passing GEMM uses). Softmax over g via shfl_xor within 16-lane groups
// (D cols = g = l16). P bounced through 512B LDS to A-layout; PV = 4x
// zero-padded mfma_16x16x32 (quads 2-3 hold k>=16 -> zero). Store into the
// "buggy reshape" position X2[b, h*128 + n/16, (n%16)*64 + d].
// ---------------------------------------------------------------------------
__global__ __launch_bounds__(256) void attn_kernel(const uint16_t* __restrict__ qb,
                                                   const uint16_t* __restrict__ kb,
                                                   const uint16_t* __restrict__ vb,
                                                   uint16_t* __restrict__ x2b) {
  __shared__ __align__(16) uint16_t plds[4][16 * 16];  // per-wave P (16x16 bf16)

  const int tid = threadIdx.x;
  const int wave = tid >> 6;
  const int lane = tid & 63;
  const int quad = lane >> 4;
  const int l16 = lane & 15;
  const int token = blockIdx.x * 4 + wave;
  const int b = token >> 11;
  const int n = token & 2047;
  const size_t base = (size_t)token * 1024;

  // --- S = Q K^T (16x16, K=64) ---
  const uint16_t* qrow = qb + base + l16 * 64 + quad * 8;
  const uint16_t* krow = kb + base + l16 * 64 + quad * 8;
  s16x8 aq0 = *(const s16x8*)qrow;
  s16x8 aq1 = *(const s16x8*)(qrow + 32);
  s16x8 bk0 = *(const s16x8*)krow;
  s16x8 bk1 = *(const s16x8*)(krow + 32);
  f32x4 s = (f32x4){0.f, 0.f, 0.f, 0.f};
  s = __builtin_amdgcn_mfma_f32_16x16x32_bf16(aq0, bk0, s, 0, 0, 0);
  s = __builtin_amdgcn_mfma_f32_16x16x32_bf16(aq1, bk1, s, 0, 0, 0);
  // lane holds S[h=quad*4+r][g=l16], r=0..3

  // --- softmax over g (across the 16 lanes sharing quad) ---
  float p[4];
#pragma unroll
  for (int r = 0; r < 4; ++r) {
    float v = s[r] * 0.125f;  // SCALE = 64^-0.5
    float mx = v;
#pragma unroll
    for (int off = 1; off < 16; off <<= 1) mx = fmaxf(mx, __shfl_xor(mx, off));
    float e = __expf(v - mx);
    float sum = e;
#pragma unroll
    for (int off = 1; off < 16; off <<= 1) sum += __shfl_xor(sum, off);
    p[r] = e / sum;
  }

  // --- transpose P to A-layout via LDS ---
  uint16_t* pb = plds[wave];
#pragma unroll
  for (int r = 0; r < 4; ++r) pb[(quad * 4 + r) * 16 + l16] = f2bf(p[r]);
  __syncthreads();
  s16x8 ap = (s16x8){0, 0, 0, 0, 0, 0, 0, 0};
  if (quad < 2) ap = *(const s16x8*)&pb[l16 * 16 + quad * 8];  // P[l16][quad*8+j]

  // --- V B-frags: B[n=d][k=g] = V[g][d]; g = quad*8+j valid only quad<2 ---
  s16x8 bv[4];
#pragma unroll
  for (int c = 0; c < 4; ++c) bv[c] = (s16x8){0, 0, 0, 0, 0, 0, 0, 0};
  if (quad < 2) {
    const uint16_t* vtok = vb + base + quad * 8 * 64 + l16;
#pragma unroll
    for (int c = 0; c < 4; ++c)
#pragma unroll
      for (int j = 0; j < 8; ++j) bv[c][j] = (short)vtok[j * 64 + c * 16];
  }

  // --- X = P V (16x64) ---
  f32x4 xacc[4];
#pragma unroll
  for (int c = 0; c < 4; ++c) {
    xacc[c] = (f32x4){0.f, 0.f, 0.f, 0.f};
    xacc[c] = __builtin_amdgcn_mfma_f32_16x16x32_bf16(ap, bv[c], xacc[c], 0, 0, 0);
  }

  // --- store: lane has x[h=quad*4+r][d=c*16+l16] ---
  uint16_t* xout = x2b + (size_t)b * (2048 * 1024) + (size_t)(n & 15) * 64 + (size_t)(n >> 4) * 1024;
#pragma unroll
  for (int c = 0; c < 4; ++c) {
    const int d = c * 16 + l16;
#pragma unroll
    for (int r = 0; r < 4; ++r) {
      const int h = quad * 4 + r;
      xout[(size_t)h * 128 * 1024 + d] = f2bf(xacc[c][r]);
    }
  }
}

// ---------------------------------------------------------------------------
extern "C" void kernel_launch(void* const* d_in, const int* in_sizes, int n_in,
                              void* d_out, int out_size, void* d_ws, size_t ws_size,
                              hipStream_t stream) {
  const float* query = (const float*)d_in[0];
  const float* key = (const float*)d_in[1];
  const float* value = (const float*)d_in[2];
  // d_in[3]=xpos, d_in[4]=ypos unused (rope is None)
  const float* Wq = (const float*)d_in[5];
  const float* Wk = (const float*)d_in[6];
  const float* Wv = (const float*)d_in[7];
  const float* Wp = (const float*)d_in[8];
  const float* bp = (const float*)d_in[9];
  float* out = (float*)d_out;

  const int C = 1024;
  const int M = 8 * 2048;  // 16384 tokens
  const size_t MC = (size_t)M * C;

  // workspace layout (bf16 = uint16): q,k,v,x2 (4*32 MiB) + 4 weights (8 MiB) = 136 MiB
  uint16_t* ws = (uint16_t*)d_ws;
  uint16_t* qb = ws;
  uint16_t* kb = qb + MC;
  uint16_t* vb = kb + MC;
  uint16_t* x2b = vb + MC;
  uint16_t* wqb = x2b + MC;
  uint16_t* wkb = wqb + (size_t)C * C;
  uint16_t* wvb = wkb + (size_t)C * C;
  uint16_t* wpb = wvb + (size_t)C * C;

  // all 4 weight conversions in one launch
  cvt_w_kernel<<<dim3(4 * 131072 / 256), dim3(256), 0, stream>>>(Wq, Wk, Wv, Wp, wqb, wkb,
                                                                 wvb, wpb);

  // batched QKV projections; grid (bn, bm, problem) -- bn fastest for A reuse
  GemmBatch qkv;
  qkv.A[0] = query;  qkv.B[0] = wqb;  qkv.C[0] = qb;
  qkv.A[1] = key;    qkv.B[1] = wkb;  qkv.C[1] = kb;
  qkv.A[2] = value;  qkv.B[2] = wvb;  qkv.C[2] = vb;
  gemm_bt<true, true><<<dim3(C / 128, M / 128, 3), dim3(256), 0, stream>>>(qkv, nullptr, M,
                                                                           C, C);

  attn_kernel<<<dim3(M / 4), dim3(256), 0, stream>>>(qb, kb, vb, x2b);

  GemmBatch fin;
  fin.A[0] = x2b;  fin.B[0] = wpb;  fin.C[0] = out;
  fin.A[1] = x2b;  fin.B[1] = wpb;  fin.C[1] = out;
  fin.A[2] = x2b;  fin.B[2] = wpb;  fin.C[2] = out;
  gemm_bt<false, false><<<dim3(C / 128, M / 128, 1), dim3(256), 0, stream>>>(fin, bp, M, C,
                                                                             C);
}

// Round 4
// 477.262 us; speedup vs baseline: 1.1570x; 1.0374x over previous
//
#include <hip/hip_runtime.h>
#include <stdint.h>

#define DEV __device__ __forceinline__

using f32x4 = __attribute__((ext_vector_type(4))) float;
using s16x8 = __attribute__((ext_vector_type(8))) short;

DEV uint16_t f2bf(float f) {
  union { float f; uint32_t u; } v; v.f = f;
  uint32_t r = v.u + 0x7fffu + ((v.u >> 16) & 1u);  // round-to-nearest-even
  return (uint16_t)(r >> 16);
}
DEV uint32_t pack2(float a, float b) {
  return (uint32_t)f2bf(a) | ((uint32_t)f2bf(b) << 16);
}

// async global->LDS, 16B per lane; LDS dest = wave-uniform base + lane*16
DEV void gload_lds16(const void* g, void* l) {
  __builtin_amdgcn_global_load_lds(
      (__attribute__((address_space(1))) void*)(void*)g,
      (__attribute__((address_space(3))) void*)l, 16, 0, 0);
}

// ---------------------------------------------------------------------------
// f32 -> bf16 weights conversion, all 4 weights in one launch.
// ---------------------------------------------------------------------------
__global__ __launch_bounds__(256) void cvt_w_kernel(const float* __restrict__ Wq,
                                                    const float* __restrict__ Wk,
                                                    const float* __restrict__ Wv,
                                                    const float* __restrict__ Wp,
                                                    uint16_t* __restrict__ wqb,
                                                    uint16_t* __restrict__ wkb,
                                                    uint16_t* __restrict__ wvb,
                                                    uint16_t* __restrict__ wpb) {
  const int idx = blockIdx.x * blockDim.x + threadIdx.x;  // 4*131072 total
  const int region = idx >> 17;
  const int i = idx & 131071;
  const float* src = region == 0 ? Wq : region == 1 ? Wk : region == 2 ? Wv : Wp;
  uint16_t* dst = region == 0 ? wqb : region == 1 ? wkb : region == 2 ? wvb : wpb;
  const float4* s = (const float4*)src;
  float4 a = s[2 * i];
  float4 b = s[2 * i + 1];
  uint4 pk;
  pk.x = pack2(a.x, a.y);
  pk.y = pack2(a.z, a.w);
  pk.z = pack2(b.x, b.y);
  pk.w = pack2(b.z, b.w);
  ((uint4*)dst)[i] = pk;
}

// ---------------------------------------------------------------------------
// NT GEMM: C[m][n] = sum_k A[m][k] * B[n][k]  (+bias), bf16 MFMA 16x16x32
// Tile 128x128, BK=32, 256 threads = 4 waves, each wave 64x64 (4x4 subtiles).
// 1-D grid + XCD-stripe swizzle: hardware maps workgroup w -> XCD (w % 8);
// we give XCD x the contiguous bm stripe [x*bmpx, (x+1)*bmpx) and iterate bn
// FASTEST within the stripe, so the 8 bn-sharers of one A row-tile are
// temporally adjacent on the SAME XCD -> A hits that XCD's L2 (fetched once).
// LDS 16B-chunk XOR swizzle pc = lc ^ ((m>>1)&3): <=2-way aliasing (free).
// ---------------------------------------------------------------------------
struct GemmBatch {
  const void* A[3];
  const uint16_t* B[3];
  void* C[3];
};

template <bool A_F32, bool OUT_BF16>
__global__ __launch_bounds__(256) void gemm_bt(GemmBatch gb,
                                               const float* __restrict__ bias,
                                               int M, int N, int K) {
  constexpr int BM = 128, BN = 128, BK = 32;
  __shared__ __align__(16) uint16_t Alds[BM * BK];
  __shared__ __align__(16) uint16_t Blds[BN * BK];

  // XCD-stripe decode: w = xcd + 8*(bn + nbn*(bml + bmpx*z))
  const int w = blockIdx.x;
  const int xcd = w & 7;
  int local = w >> 3;
  const int nbn = N >> 7;
  const int bmpx = (M >> 7) >> 3;
  const int bn = local % nbn;
  local /= nbn;
  const int bml = local % bmpx;
  const int z = local / bmpx;
  const int bm0 = (xcd * bmpx + bml) * BM;
  const int bn0 = bn * BN;

  const void* __restrict__ Ap = gb.A[z];
  const uint16_t* __restrict__ Bp = gb.B[z];
  void* __restrict__ Cp = gb.C[z];

  const int tid = threadIdx.x;
  const int wave = tid >> 6;
  const int lane = tid & 63;
  const int quad = lane >> 4;
  const int l16 = lane & 15;
  const int wm = (wave >> 1) * 64;
  const int wn = (wave & 1) * 64;

  f32x4 acc[4][4];
#pragma unroll
  for (int i = 0; i < 4; ++i)
#pragma unroll
    for (int j = 0; j < 4; ++j) acc[i][j] = (f32x4){0.f, 0.f, 0.f, 0.f};

  // B tile async staging: chunk p = wave*128 + j*64 + lane lands at LDS byte p*16
  const uint16_t* bsrc[2];
  uint16_t* bdst[2];
#pragma unroll
  for (int j = 0; j < 2; ++j) {
    const int p = wave * 128 + j * 64 + lane;
    const int m = p >> 2;
    const int lc = (p & 3) ^ ((m >> 1) & 3);
    bsrc[j] = Bp + (size_t)(bn0 + m) * K + lc * 8;
    bdst[j] = &Blds[(wave * 128 + j * 64) * 8];  // wave-uniform base
  }

  const float* asrcf[2];
  int adst_f[2];
  const uint16_t* asrc16[2];
  uint16_t* adst16[2];
  float4 cur[2][2], nxt[2][2];
  if constexpr (A_F32) {
    // register staging with cvt: thread handles chunks tid and tid+256
#pragma unroll
    for (int c = 0; c < 2; ++c) {
      const int p = tid + c * 256;
      const int m = p >> 2;
      const int lc = (p & 3) ^ ((m >> 1) & 3);
      asrcf[c] = (const float*)Ap + (size_t)(bm0 + m) * K + lc * 8;
      adst_f[c] = p * 8;  // ushort index; byte p*16
    }
    // prologue: load iter-0 A regs
#pragma unroll
    for (int c = 0; c < 2; ++c) {
      const float4* g = (const float4*)asrcf[c];
      cur[c][0] = g[0];
      cur[c][1] = g[1];
    }
  } else {
#pragma unroll
    for (int j = 0; j < 2; ++j) {
      const int p = wave * 128 + j * 64 + lane;
      const int m = p >> 2;
      const int lc = (p & 3) ^ ((m >> 1) & 3);
      asrc16[j] = (const uint16_t*)Ap + (size_t)(bm0 + m) * K + lc * 8;
      adst16[j] = &Alds[(wave * 128 + j * 64) * 8];
    }
  }

  for (int k0 = 0; k0 < K; k0 += BK) {
    // issue async B staging first (stays in flight through the VALU below)
#pragma unroll
    for (int j = 0; j < 2; ++j) gload_lds16(bsrc[j] + k0, bdst[j]);
    if constexpr (!A_F32) {
#pragma unroll
      for (int j = 0; j < 2; ++j) gload_lds16(asrc16[j] + k0, adst16[j]);
    } else {
      // pack current A regs (loaded >=1 iter ago) -> LDS
#pragma unroll
      for (int c = 0; c < 2; ++c) {
        uint4 pk;
        pk.x = pack2(cur[c][0].x, cur[c][0].y);
        pk.y = pack2(cur[c][0].z, cur[c][0].w);
        pk.z = pack2(cur[c][1].x, cur[c][1].y);
        pk.w = pack2(cur[c][1].z, cur[c][1].w);
        *(uint4*)&Alds[adst_f[c]] = pk;
      }
      // prefetch next iter's A f32 into regs; the barrier's vmcnt(0) drain
      // (needed for B's global_load_lds anyway) absorbs this latency.
      if (k0 + BK < K) {
#pragma unroll
        for (int c = 0; c < 2; ++c) {
          const float4* g = (const float4*)(asrcf[c] + k0 + BK);
          nxt[c][0] = g[0];
          nxt[c][1] = g[1];
        }
      }
    }
    __syncthreads();

    s16x8 af[4], bfv[4];
#pragma unroll
    for (int s = 0; s < 4; ++s) {
      const int ml = wm + s * 16 + l16;
      const int ca = ml * 4 + (quad ^ ((ml >> 1) & 3));
      af[s] = *(const s16x8*)&Alds[ca * 8];
      const int nl = wn + s * 16 + l16;
      const int cb = nl * 4 + (quad ^ ((nl >> 1) & 3));
      bfv[s] = *(const s16x8*)&Blds[cb * 8];
    }
#pragma unroll
    for (int sm = 0; sm < 4; ++sm)
#pragma unroll
      for (int sn = 0; sn < 4; ++sn)
        acc[sm][sn] =
            __builtin_amdgcn_mfma_f32_16x16x32_bf16(af[sm], bfv[sn], acc[sm][sn], 0, 0, 0);
    __syncthreads();

    if constexpr (A_F32) {
#pragma unroll
      for (int c = 0; c < 2; ++c) {
        cur[c][0] = nxt[c][0];
        cur[c][1] = nxt[c][1];
      }
    }
  }

  // epilogue: C/D layout col = lane&15, row = quad*4 + r (m89-verified)
#pragma unroll
  for (int sm = 0; sm < 4; ++sm) {
    const int mrow = bm0 + wm + sm * 16 + quad * 4;
#pragma unroll
    for (int sn = 0; sn < 4; ++sn) {
      const int ncol = bn0 + wn + sn * 16 + l16;
      if constexpr (OUT_BF16) {
        uint16_t* Cb = (uint16_t*)Cp;
#pragma unroll
        for (int r = 0; r < 4; ++r) Cb[(size_t)(mrow + r) * N + ncol] = f2bf(acc[sm][sn][r]);
      } else {
        float* Cf = (float*)Cp;
        const float bv = bias[ncol];
#pragma unroll
        for (int r = 0; r < 4; ++r) Cf[(size_t)(mrow + r) * N + ncol] = acc[sm][sn][r] + bv;
      }
    }
  }
}

// ---------------------------------------------------------------------------
// MFMA attention: one WAVE per token. S = Q·K^T via 2x mfma_16x16x32_bf16;
// softmax over g via shfl_xor within 16-lane groups; P through 512B LDS to
// A-layout; V staged coalesced into an XOR-swizzled LDS tile (chunk cc of row
// g stored at cc ^ (2*(g>>3)) so the column-wise B-frag reads are
// bank-conflict-free); PV = 4x zero-padded mfma_16x16x32.
// Store into "buggy reshape" position X2[b, h*128 + n/16, (n%16)*64 + d].
// ---------------------------------------------------------------------------
__global__ __launch_bounds__(256) void attn_kernel(const uint16_t* __restrict__ qb,
                                                   const uint16_t* __restrict__ kb,
                                                   const uint16_t* __restrict__ vb,
                                                   uint16_t* __restrict__ x2b) {
  __shared__ __align__(16) uint16_t plds[4][16 * 16];  // per-wave P (16x16 bf16)
  __shared__ __align__(16) uint16_t vlds[4][16 * 64];  // per-wave V tile, swizzled

  const int tid = threadIdx.x;
  const int wave = tid >> 6;
  const int lane = tid & 63;
  const int quad = lane >> 4;
  const int l16 = lane & 15;
  const int token = blockIdx.x * 4 + wave;
  const int b = token >> 11;
  const int n = token & 2047;
  const size_t base = (size_t)token * 1024;

  // --- stage V (coalesced 16B chunks, XOR-swizzled columns) ---
  {
    const uint16_t* vt = vb + base;  // 16x64 bf16, contiguous
    uint16_t* vl = vlds[wave];
#pragma unroll
    for (int c2 = 0; c2 < 2; ++c2) {
      const int p = lane + c2 * 64;  // chunk index; src = 16B at p*16
      const int g = p >> 3;
      const int cc = p & 7;
      const int cs = cc ^ (2 * (g >> 3));
      *(uint4*)&vl[g * 64 + cs * 8] = *(const uint4*)&vt[p * 8];
    }
  }

  // --- S = Q K^T (16x16, K=64) ---
  const uint16_t* qrow = qb + base + l16 * 64 + quad * 8;
  const uint16_t* krow = kb + base + l16 * 64 + quad * 8;
  s16x8 aq0 = *(const s16x8*)qrow;
  s16x8 aq1 = *(const s16x8*)(qrow + 32);
  s16x8 bk0 = *(const s16x8*)krow;
  s16x8 bk1 = *(const s16x8*)(krow + 32);
  f32x4 s = (f32x4){0.f, 0.f, 0.f, 0.f};
  s = __builtin_amdgcn_mfma_f32_16x16x32_bf16(aq0, bk0, s, 0, 0, 0);
  s = __builtin_amdgcn_mfma_f32_16x16x32_bf16(aq1, bk1, s, 0, 0, 0);
  // lane holds S[h=quad*4+r][g=l16], r=0..3

  // --- softmax over g (across the 16 lanes sharing quad) ---
  float p[4];
#pragma unroll
  for (int r = 0; r < 4; ++r) {
    float v = s[r] * 0.125f;  // SCALE = 64^-0.5
    float mx = v;
#pragma unroll
    for (int off = 1; off < 16; off <<= 1) mx = fmaxf(mx, __shfl_xor(mx, off));
    float e = __expf(v - mx);
    float sum = e;
#pragma unroll
    for (int off = 1; off < 16; off <<= 1) sum += __shfl_xor(sum, off);
    p[r] = e / sum;
  }

  // --- transpose P to A-layout via LDS ---
  uint16_t* pb = plds[wave];
#pragma unroll
  for (int r = 0; r < 4; ++r) pb[(quad * 4 + r) * 16 + l16] = f2bf(p[r]);
  __syncthreads();
  s16x8 ap = (s16x8){0, 0, 0, 0, 0, 0, 0, 0};
  if (quad < 2) ap = *(const s16x8*)&pb[l16 * 16 + quad * 8];  // P[l16][quad*8+j]

  // --- V B-frags from LDS: bv[c][j] = V[g=quad*8+j][d=c*16+l16] ---
  s16x8 bv[4];
#pragma unroll
  for (int c = 0; c < 4; ++c) bv[c] = (s16x8){0, 0, 0, 0, 0, 0, 0, 0};
  if (quad < 2) {
    const uint16_t* vl = vlds[wave];
#pragma unroll
    for (int c = 0; c < 4; ++c) {
      const int cc = c * 2 + (l16 >> 3);
      const int dlo = l16 & 7;
#pragma unroll
      for (int j = 0; j < 8; ++j) {
        const int g = quad * 8 + j;
        const int cs = cc ^ (2 * (g >> 3));
        bv[c][j] = (short)vl[g * 64 + cs * 8 + dlo];
      }
    }
  }

  // --- X = P V (16x64) ---
  f32x4 xacc[4];
#pragma unroll
  for (int c = 0; c < 4; ++c) {
    xacc[c] = (f32x4){0.f, 0.f, 0.f, 0.f};
    xacc[c] = __builtin_amdgcn_mfma_f32_16x16x32_bf16(ap, bv[c], xacc[c], 0, 0, 0);
  }

  // --- store: lane has x[h=quad*4+r][d=c*16+l16] ---
  uint16_t* xout =
      x2b + (size_t)b * (2048 * 1024) + (size_t)(n & 15) * 64 + (size_t)(n >> 4) * 1024;
#pragma unroll
  for (int c = 0; c < 4; ++c) {
    const int d = c * 16 + l16;
#pragma unroll
    for (int r = 0; r < 4; ++r) {
      const int h = quad * 4 + r;
      xout[(size_t)h * 128 * 1024 + d] = f2bf(xacc[c][r]);
    }
  }
}

// ---------------------------------------------------------------------------
extern "C" void kernel_launch(void* const* d_in, const int* in_sizes, int n_in,
                              void* d_out, int out_size, void* d_ws, size_t ws_size,
                              hipStream_t stream) {
  const float* query = (const float*)d_in[0];
  const float* key = (const float*)d_in[1];
  const float* value = (const float*)d_in[2];
  // d_in[3]=xpos, d_in[4]=ypos unused (rope is None)
  const float* Wq = (const float*)d_in[5];
  const float* Wk = (const float*)d_in[6];
  const float* Wv = (const float*)d_in[7];
  const float* Wp = (const float*)d_in[8];
  const float* bp = (const float*)d_in[9];
  float* out = (float*)d_out;

  const int C = 1024;
  const int M = 8 * 2048;  // 16384 tokens
  const size_t MC = (size_t)M * C;

  // workspace layout (bf16 = uint16): q,k,v,x2 (4*32 MiB) + 4 weights (8 MiB) = 136 MiB
  uint16_t* ws = (uint16_t*)d_ws;
  uint16_t* qb = ws;
  uint16_t* kb = qb + MC;
  uint16_t* vb = kb + MC;
  uint16_t* x2b = vb + MC;
  uint16_t* wqb = x2b + MC;
  uint16_t* wkb = wqb + (size_t)C * C;
  uint16_t* wvb = wkb + (size_t)C * C;
  uint16_t* wpb = wvb + (size_t)C * C;

  // all 4 weight conversions in one launch
  cvt_w_kernel<<<dim3(4 * 131072 / 256), dim3(256), 0, stream>>>(Wq, Wk, Wv, Wp, wqb, wkb,
                                                                 wvb, wpb);

  // batched QKV projections; 1-D grid, XCD-stripe swizzle decoded in-kernel
  GemmBatch qkv;
  qkv.A[0] = query;  qkv.B[0] = wqb;  qkv.C[0] = qb;
  qkv.A[1] = key;    qkv.B[1] = wkb;  qkv.C[1] = kb;
  qkv.A[2] = value;  qkv.B[2] = wvb;  qkv.C[2] = vb;
  gemm_bt<true, true><<<dim3((M / 128) * (C / 128) * 3), dim3(256), 0, stream>>>(
      qkv, nullptr, M, C, C);

  attn_kernel<<<dim3(M / 4), dim3(256), 0, stream>>>(qb, kb, vb, x2b);

  GemmBatch fin;
  fin.A[0] = x2b;  fin.B[0] = wpb;  fin.C[0] = out;
  fin.A[1] = x2b;  fin.B[1] = wpb;  fin.C[1] = out;
  fin.A[2] = x2b;  fin.B[2] = wpb;  fin.C[2] = out;
  gemm_bt<false, false><<<dim3((M / 128) * (C / 128)), dim3(256), 0, stream>>>(fin, bp, M,
                                                                               C, C);
}